// Round 1
// baseline (207.867 us; speedup 1.0000x reference)
//
#include <hip/hip_runtime.h>

#define N_SAMPLE 5

__global__ __launch_bounds__(256) void lddt_count_kernel(
    const float* __restrict__ pred,    // [N_SAMPLE][n_atom][3]
    const float* __restrict__ truec,   // [n_atom][3]
    const int*   __restrict__ l_index, // [n_pairs]
    const int*   __restrict__ m_index, // [n_pairs]
    unsigned int* __restrict__ counters, // [N_SAMPLE]
    int n_pairs, int n_atom)
{
    unsigned int cnt[N_SAMPLE];
#pragma unroll
    for (int s = 0; s < N_SAMPLE; ++s) cnt[s] = 0u;

    const int tid    = blockIdx.x * blockDim.x + threadIdx.x;
    const int stride = gridDim.x * blockDim.x;
    const int sstride = n_atom * 3;

    for (int p = tid; p < n_pairs; p += stride) {
        const int l = l_index[p] * 3;
        const int m = m_index[p] * 3;

        float tx = truec[l]     - truec[m];
        float ty = truec[l + 1] - truec[m + 1];
        float tz = truec[l + 2] - truec[m + 2];
        float true_d = sqrtf(tx * tx + ty * ty + tz * tz);

#pragma unroll
        for (int s = 0; s < N_SAMPLE; ++s) {
            const float* ps = pred + (long)s * sstride;
            float dx = ps[l]     - ps[m];
            float dy = ps[l + 1] - ps[m + 1];
            float dz = ps[l + 2] - ps[m + 2];
            float pd = sqrtf(dx * dx + dy * dy + dz * dz);
            float err = fabsf(pd - true_d);
            unsigned int c = (unsigned int)(err < 0.5f) + (unsigned int)(err < 1.0f)
                           + (unsigned int)(err < 2.0f) + (unsigned int)(err < 4.0f);
            cnt[s] += c;
        }
    }

    // wave (64-lane) reduction per sample
#pragma unroll
    for (int s = 0; s < N_SAMPLE; ++s) {
        unsigned int v = cnt[s];
#pragma unroll
        for (int off = 32; off >= 1; off >>= 1)
            v += (unsigned int)__shfl_down((int)v, off, 64);
        cnt[s] = v;
    }

    __shared__ unsigned int smem[N_SAMPLE][4]; // 4 waves per 256-thread block
    const int lane = threadIdx.x & 63;
    const int wid  = threadIdx.x >> 6;
    if (lane == 0) {
#pragma unroll
        for (int s = 0; s < N_SAMPLE; ++s) smem[s][wid] = cnt[s];
    }
    __syncthreads();
    if (threadIdx.x < N_SAMPLE) {
        unsigned int t = smem[threadIdx.x][0] + smem[threadIdx.x][1]
                       + smem[threadIdx.x][2] + smem[threadIdx.x][3];
        atomicAdd(&counters[threadIdx.x], t);
    }
}

__global__ void lddt_finalize(const unsigned int* __restrict__ counters,
                              float* __restrict__ out, int n_pairs)
{
    const int i = threadIdx.x;
    if (i < N_SAMPLE) {
        out[i] = (float)counters[i] / (4.0f * (float)n_pairs);
    }
}

extern "C" void kernel_launch(void* const* d_in, const int* in_sizes, int n_in,
                              void* d_out, int out_size, void* d_ws, size_t ws_size,
                              hipStream_t stream) {
    const float* pred   = (const float*)d_in[0]; // [5, n_atom, 3]
    const float* truec  = (const float*)d_in[1]; // [n_atom, 3]
    const int* l_index  = (const int*)d_in[2];
    const int* m_index  = (const int*)d_in[3];
    float* out = (float*)d_out;

    const int n_pairs = in_sizes[2];
    const int n_atom  = in_sizes[1] / 3;

    unsigned int* counters = (unsigned int*)d_ws;
    hipMemsetAsync(counters, 0, N_SAMPLE * sizeof(unsigned int), stream);

    const int block = 256;
    const int grid  = 2048; // 32 waves/CU across 256 CUs; grid-stride covers 4M pairs

    lddt_count_kernel<<<grid, block, 0, stream>>>(pred, truec, l_index, m_index,
                                                  counters, n_pairs, n_atom);
    lddt_finalize<<<1, 64, 0, stream>>>(counters, out, n_pairs);
}

// Round 2
// 132.047 us; speedup vs baseline: 1.5742x; 1.5742x over previous
//
#include <hip/hip_runtime.h>

#define N_SAMPLE 5
#define PACK_STRIDE 20  // floats per atom: true.xyz + 5*pred.xyz = 18, pad to 20 (80 B, 16B-aligned)

// ---------- repack: [5][A][3] pred + [A][3] true  ->  [A][20] interleaved ----------
__global__ __launch_bounds__(256) void repack_kernel(
    const float* __restrict__ pred,
    const float* __restrict__ truec,
    float* __restrict__ packed,
    int n_atom)
{
    int a = blockIdx.x * blockDim.x + threadIdx.x;
    if (a >= n_atom) return;
    float f[PACK_STRIDE];
    f[0] = truec[a * 3 + 0];
    f[1] = truec[a * 3 + 1];
    f[2] = truec[a * 3 + 2];
#pragma unroll
    for (int s = 0; s < N_SAMPLE; ++s) {
        const float* ps = pred + (long)s * n_atom * 3 + (long)a * 3;
        f[3 + s * 3 + 0] = ps[0];
        f[3 + s * 3 + 1] = ps[1];
        f[3 + s * 3 + 2] = ps[2];
    }
    f[18] = 0.0f;
    f[19] = 0.0f;
    float4* dst = (float4*)(packed + (long)a * PACK_STRIDE);
#pragma unroll
    for (int q = 0; q < 5; ++q) {
        dst[q] = make_float4(f[q * 4 + 0], f[q * 4 + 1], f[q * 4 + 2], f[q * 4 + 3]);
    }
}

// ---------- count ----------
__device__ __forceinline__ void process_pair(const float* __restrict__ packed,
                                             int l, int m,
                                             unsigned int cnt[N_SAMPLE])
{
    union Rec { float4 v[5]; float f[PACK_STRIDE]; } L, M;
    const float4* pl = (const float4*)(packed + (long)l * PACK_STRIDE);
    const float4* pm = (const float4*)(packed + (long)m * PACK_STRIDE);
#pragma unroll
    for (int q = 0; q < 5; ++q) { L.v[q] = pl[q]; M.v[q] = pm[q]; }

    float tx = L.f[0] - M.f[0];
    float ty = L.f[1] - M.f[1];
    float tz = L.f[2] - M.f[2];
    float td = sqrtf(tx * tx + ty * ty + tz * tz);

#pragma unroll
    for (int s = 0; s < N_SAMPLE; ++s) {
        float dx = L.f[3 + s * 3 + 0] - M.f[3 + s * 3 + 0];
        float dy = L.f[3 + s * 3 + 1] - M.f[3 + s * 3 + 1];
        float dz = L.f[3 + s * 3 + 2] - M.f[3 + s * 3 + 2];
        float pd = sqrtf(dx * dx + dy * dy + dz * dz);
        float err = fabsf(pd - td);
        cnt[s] += (unsigned int)((err < 0.5f) + (err < 1.0f) + (err < 2.0f) + (err < 4.0f));
    }
}

__global__ __launch_bounds__(256) void lddt_count_kernel(
    const float* __restrict__ packed,
    const int*   __restrict__ l_index,
    const int*   __restrict__ m_index,
    unsigned int* __restrict__ counters,
    int n_pairs)
{
    unsigned int cnt[N_SAMPLE];
#pragma unroll
    for (int s = 0; s < N_SAMPLE; ++s) cnt[s] = 0u;

    const int tid    = blockIdx.x * blockDim.x + threadIdx.x;
    const int stride = gridDim.x * blockDim.x;

    // two pairs per iteration for doubled memory-level parallelism
    const int npair2 = n_pairs >> 1;
    const int2* l2 = (const int2*)l_index;
    const int2* m2 = (const int2*)m_index;
    for (int i = tid; i < npair2; i += stride) {
        int2 lp = l2[i];
        int2 mp = m2[i];
        process_pair(packed, lp.x, mp.x, cnt);
        process_pair(packed, lp.y, mp.y, cnt);
    }
    // tail (n_pairs odd)
    for (int p = (npair2 << 1) + tid; p < n_pairs; p += stride) {
        process_pair(packed, l_index[p], m_index[p], cnt);
    }

    // wave (64-lane) reduction per sample
#pragma unroll
    for (int s = 0; s < N_SAMPLE; ++s) {
        unsigned int v = cnt[s];
#pragma unroll
        for (int off = 32; off >= 1; off >>= 1)
            v += (unsigned int)__shfl_down((int)v, off, 64);
        cnt[s] = v;
    }

    __shared__ unsigned int smem[N_SAMPLE][4];
    const int lane = threadIdx.x & 63;
    const int wid  = threadIdx.x >> 6;
    if (lane == 0) {
#pragma unroll
        for (int s = 0; s < N_SAMPLE; ++s) smem[s][wid] = cnt[s];
    }
    __syncthreads();
    if (threadIdx.x < N_SAMPLE) {
        unsigned int t = smem[threadIdx.x][0] + smem[threadIdx.x][1]
                       + smem[threadIdx.x][2] + smem[threadIdx.x][3];
        atomicAdd(&counters[threadIdx.x], t);
    }
}

__global__ void lddt_finalize(const unsigned int* __restrict__ counters,
                              float* __restrict__ out, int n_pairs)
{
    const int i = threadIdx.x;
    if (i < N_SAMPLE) {
        out[i] = (float)counters[i] / (4.0f * (float)n_pairs);
    }
}

extern "C" void kernel_launch(void* const* d_in, const int* in_sizes, int n_in,
                              void* d_out, int out_size, void* d_ws, size_t ws_size,
                              hipStream_t stream) {
    const float* pred   = (const float*)d_in[0]; // [5, n_atom, 3]
    const float* truec  = (const float*)d_in[1]; // [n_atom, 3]
    const int* l_index  = (const int*)d_in[2];
    const int* m_index  = (const int*)d_in[3];
    float* out = (float*)d_out;

    const int n_pairs = in_sizes[2];
    const int n_atom  = in_sizes[1] / 3;

    unsigned int* counters = (unsigned int*)d_ws;                 // 5 u32 at offset 0
    float* packed = (float*)((char*)d_ws + 256);                  // [n_atom][20] floats

    hipMemsetAsync(counters, 0, N_SAMPLE * sizeof(unsigned int), stream);

    repack_kernel<<<(n_atom + 255) / 256, 256, 0, stream>>>(pred, truec, packed, n_atom);

    const int block = 256;
    const int grid  = 2048;
    lddt_count_kernel<<<grid, block, 0, stream>>>(packed, l_index, m_index,
                                                  counters, n_pairs);
    lddt_finalize<<<1, 64, 0, stream>>>(counters, out, n_pairs);
}

// Round 3
// 61.316 us; speedup vs baseline: 3.3901x; 2.1535x over previous
//
#include <hip/hip_runtime.h>
#include <hip/hip_fp16.h>

#define N_SAMPLE 5
#define REC_STRIDE_BYTES 64  // 18 halfs (36B) padded to one 64B line per atom

// ---------- repack: [5][A][3] pred + [A][3] true -> [A][64B] fp16 records ----------
__global__ __launch_bounds__(256) void repack_kernel(
    const float* __restrict__ pred,
    const float* __restrict__ truec,
    unsigned int* __restrict__ packed,   // viewed as u32 words
    int n_atom)
{
    int a = blockIdx.x * blockDim.x + threadIdx.x;
    if (a >= n_atom) return;

    float f[18];
    f[0] = truec[a * 3 + 0];
    f[1] = truec[a * 3 + 1];
    f[2] = truec[a * 3 + 2];
#pragma unroll
    for (int s = 0; s < N_SAMPLE; ++s) {
        const float* ps = pred + (long)s * n_atom * 3 + (long)a * 3;
        f[3 + s * 3 + 0] = ps[0];
        f[3 + s * 3 + 1] = ps[1];
        f[3 + s * 3 + 2] = ps[2];
    }
    unsigned int u[9];
#pragma unroll
    for (int j = 0; j < 9; ++j) {
        __half2 h2 = __floats2half2_rn(f[2 * j], f[2 * j + 1]);
        u[j] = *reinterpret_cast<unsigned int*>(&h2);
    }
    unsigned int* dst = packed + (long)a * (REC_STRIDE_BYTES / 4);
    *(uint4*)(dst + 0) = make_uint4(u[0], u[1], u[2], u[3]);
    *(uint4*)(dst + 4) = make_uint4(u[4], u[5], u[6], u[7]);
    dst[8] = u[8];
}

// ---------- count ----------
struct Rec { unsigned int u[9]; };

__device__ __forceinline__ Rec load_rec(const unsigned int* __restrict__ packed, int a)
{
    const unsigned int* p = packed + (long)a * (REC_STRIDE_BYTES / 4);
    Rec r;
    uint4 q0 = *(const uint4*)(p + 0);
    uint4 q1 = *(const uint4*)(p + 4);
    r.u[0] = q0.x; r.u[1] = q0.y; r.u[2] = q0.z; r.u[3] = q0.w;
    r.u[4] = q1.x; r.u[5] = q1.y; r.u[6] = q1.z; r.u[7] = q1.w;
    r.u[8] = p[8];
    return r;
}

__device__ __forceinline__ void unpack(const Rec& r, float f[18])
{
#pragma unroll
    for (int j = 0; j < 9; ++j) {
        __half2 h2 = *reinterpret_cast<const __half2*>(&r.u[j]);
        float2 v = __half22float2(h2);
        f[2 * j] = v.x; f[2 * j + 1] = v.y;
    }
}

__device__ __forceinline__ void process_pair(const Rec& lr, const Rec& mr,
                                             unsigned int cnt[N_SAMPLE])
{
    float L[18], M[18];
    unpack(lr, L);
    unpack(mr, M);

    float tx = L[0] - M[0];
    float ty = L[1] - M[1];
    float tz = L[2] - M[2];
    float td = sqrtf(tx * tx + ty * ty + tz * tz);

#pragma unroll
    for (int s = 0; s < N_SAMPLE; ++s) {
        float dx = L[3 + s * 3 + 0] - M[3 + s * 3 + 0];
        float dy = L[3 + s * 3 + 1] - M[3 + s * 3 + 1];
        float dz = L[3 + s * 3 + 2] - M[3 + s * 3 + 2];
        float pd = sqrtf(dx * dx + dy * dy + dz * dz);
        float err = fabsf(pd - td);
        cnt[s] += (unsigned int)((err < 0.5f) + (err < 1.0f) + (err < 2.0f) + (err < 4.0f));
    }
}

__global__ __launch_bounds__(256) void lddt_count_kernel(
    const unsigned int* __restrict__ packed,
    const int*   __restrict__ l_index,
    const int*   __restrict__ m_index,
    unsigned int* __restrict__ counters,
    int n_pairs)
{
    unsigned int cnt[N_SAMPLE];
#pragma unroll
    for (int s = 0; s < N_SAMPLE; ++s) cnt[s] = 0u;

    const int tid    = blockIdx.x * blockDim.x + threadIdx.x;
    const int stride = gridDim.x * blockDim.x;

    // four pairs per iteration for memory-level parallelism
    const int npair4 = n_pairs >> 2;
    const int4* l4 = (const int4*)l_index;
    const int4* m4 = (const int4*)m_index;
    for (int i = tid; i < npair4; i += stride) {
        int4 lp = l4[i];
        int4 mp = m4[i];
        Rec l0 = load_rec(packed, lp.x);
        Rec m0 = load_rec(packed, mp.x);
        Rec l1 = load_rec(packed, lp.y);
        Rec m1 = load_rec(packed, mp.y);
        Rec l2 = load_rec(packed, lp.z);
        Rec m2 = load_rec(packed, mp.z);
        Rec l3 = load_rec(packed, lp.w);
        Rec m3 = load_rec(packed, mp.w);
        process_pair(l0, m0, cnt);
        process_pair(l1, m1, cnt);
        process_pair(l2, m2, cnt);
        process_pair(l3, m3, cnt);
    }
    // tail
    for (int p = (npair4 << 2) + tid; p < n_pairs; p += stride) {
        Rec lr = load_rec(packed, l_index[p]);
        Rec mr = load_rec(packed, m_index[p]);
        process_pair(lr, mr, cnt);
    }

    // wave (64-lane) reduction per sample
#pragma unroll
    for (int s = 0; s < N_SAMPLE; ++s) {
        unsigned int v = cnt[s];
#pragma unroll
        for (int off = 32; off >= 1; off >>= 1)
            v += (unsigned int)__shfl_down((int)v, off, 64);
        cnt[s] = v;
    }

    __shared__ unsigned int smem[N_SAMPLE][4];
    const int lane = threadIdx.x & 63;
    const int wid  = threadIdx.x >> 6;
    if (lane == 0) {
#pragma unroll
        for (int s = 0; s < N_SAMPLE; ++s) smem[s][wid] = cnt[s];
    }
    __syncthreads();
    if (threadIdx.x < N_SAMPLE) {
        unsigned int t = smem[threadIdx.x][0] + smem[threadIdx.x][1]
                       + smem[threadIdx.x][2] + smem[threadIdx.x][3];
        atomicAdd(&counters[threadIdx.x], t);
    }
}

__global__ void lddt_finalize(const unsigned int* __restrict__ counters,
                              float* __restrict__ out, int n_pairs)
{
    const int i = threadIdx.x;
    if (i < N_SAMPLE) {
        out[i] = (float)counters[i] / (4.0f * (float)n_pairs);
    }
}

extern "C" void kernel_launch(void* const* d_in, const int* in_sizes, int n_in,
                              void* d_out, int out_size, void* d_ws, size_t ws_size,
                              hipStream_t stream) {
    const float* pred   = (const float*)d_in[0]; // [5, n_atom, 3]
    const float* truec  = (const float*)d_in[1]; // [n_atom, 3]
    const int* l_index  = (const int*)d_in[2];
    const int* m_index  = (const int*)d_in[3];
    float* out = (float*)d_out;

    const int n_pairs = in_sizes[2];
    const int n_atom  = in_sizes[1] / 3;

    unsigned int* counters = (unsigned int*)d_ws;                  // 5 u32 at offset 0
    unsigned int* packed   = (unsigned int*)((char*)d_ws + 256);   // [n_atom][16] u32 (64B records)

    hipMemsetAsync(counters, 0, N_SAMPLE * sizeof(unsigned int), stream);

    repack_kernel<<<(n_atom + 255) / 256, 256, 0, stream>>>(pred, truec, packed, n_atom);

    const int block = 256;
    const int grid  = 2048;
    lddt_count_kernel<<<grid, block, 0, stream>>>(packed, l_index, m_index,
                                                  counters, n_pairs);
    lddt_finalize<<<1, 64, 0, stream>>>(counters, out, n_pairs);
}